// Round 5
// baseline (544.519 us; speedup 1.0000x reference)
//
#include <hip/hip_runtime.h>
#include <stdint.h>

// Top-k (k=10% of N) by value over flat fp32; scatter values back, zeros
// elsewhere. 8 dispatches total (R4 lesson: ~10us/dispatch gap dominates).
//   1 prep   (256 blk): zero ws metadata/hists in-kernel; gather 64K sample
//   2 refine (1 blk): two-level sample scan -> 2^20-code window estimate
//   3 main   (2048 blk): THE full pass: read x, tentative out write
//            (above->x else 0), window per-code hist + chunk sums, exact
//            coarse 2048-bin hist (for fallback), compacted in-window list
//            into 64 striped segments (1 returning atomic per block)
//   4 final  (1 blk): exact threshold t_u + tie count, or fallback setup
//   5 fix    (2048 blk): OK: patch listed in-window winners (~35MB traffic)
//                        !OK: fallback exact per-code hist of coarse bin
//   6 post   (1 blk): OK: stable tie-fix; !OK: fallback scan -> t_u
//   7 fb_scatter (2048 blk): full exact re-scatter, no-op when OK
//   8 fb_post    (1 blk): tie-fix for fallback path, no-op when OK
// Lessons: R2 - no bursts of same-address returning atomics (78ns each,
//          serialized); R3 - no strided sampling; R4 - dispatch gaps ~10us.

#define WBITS 20u
#define WSIZE (1u << WBITS)
#define SEG 64
#define SEGCAP 32768
#define EQ_CAP 65536
#define MAIN_GRID 2048
#define BLK 256

#define SC_WLO   0
#define SC_ABOVE 1
#define SC_TU    2
#define SC_NEED  3
#define SC_EQN   4
#define SC_OK    5
#define SC_CB    6
#define SC_CBKR  7
#define SC_OVF   8

__device__ __forceinline__ unsigned int f2u(float x) {
    unsigned int b = __float_as_uint(x);
    return (b & 0x80000000u) ? ~b : (b | 0x80000000u);
}
__device__ __forceinline__ float u2f(unsigned int u) {
    return __uint_as_float((u & 0x80000000u) ? (u & 0x7FFFFFFFu) : ~u);
}

__device__ __forceinline__ unsigned int block_exscan256(unsigned int v,
                                                        unsigned int* lds,
                                                        int tid)
{
    lds[tid] = v;
    __syncthreads();
    for (int off = 1; off < 256; off <<= 1) {
        unsigned int t = (tid >= off) ? lds[tid - off] : 0u;
        __syncthreads();
        lds[tid] += t;
        __syncthreads();
    }
    return lds[tid] - v;
}

// ---- 1: zero ws metadata + hists; gather coalesced sample ----
__global__ void __launch_bounds__(256)
prep_kernel(const float* __restrict__ x, long long N,
            unsigned int* __restrict__ samp,
            unsigned int* __restrict__ fine,      // 2^20 u32
            unsigned int* __restrict__ hist2,     // 2^21 u32
            unsigned int* __restrict__ small)     // first 32KB of ws
{
    int g = blockIdx.x * 256 + threadIdx.x;       // 0..65535
    if (g < 8192) small[g] = 0u;                  // sc+segctr+csum+csum2+gcoarse
    for (int i = g; i < (1 << 20); i += 65536) fine[i] = 0u;
    for (int i = g; i < (1 << 21); i += 65536) hist2[i] = 0u;
    long long cstride = N >> 8; if (cstride < 1) cstride = 1;
    long long idx = (long long)blockIdx.x * cstride + threadIdx.x;
    if (idx >= N) idx = N - 1;
    samp[g] = f2u(x[idx]);
}

// ---- 2: two-level scan of the 64K sample -> window ----
__global__ void __launch_bounds__(256)
refine_kernel(const unsigned int* __restrict__ samp,
              unsigned int* __restrict__ sc, unsigned int ks, unsigned int NS)
{
    __shared__ unsigned int lh[2048];
    __shared__ unsigned int lds[256];
    __shared__ unsigned int sB, sKr;
    int tid = threadIdx.x;
    for (int i = tid; i < 2048; i += 256) lh[i] = 0u;
    __syncthreads();
    for (unsigned int i = tid; i < NS; i += 256) atomicAdd(&lh[samp[i] >> 21], 1u);
    __syncthreads();
    unsigned int loc[8], part = 0u;
    for (int j = 0; j < 8; ++j) { unsigned int v = lh[2047 - (tid * 8 + j)]; loc[j] = v; part += v; }
    unsigned int cum = block_exscan256(part, lds, tid);
    for (int j = 0; j < 8; ++j) {
        int bin = 2047 - (tid * 8 + j); unsigned int c = loc[j];
        if (cum < ks && cum + c >= ks) { sB = (unsigned int)bin; sKr = ks - cum; }
        cum += c;
    }
    __syncthreads();
    unsigned int B = sB, kr = sKr;
    for (int i = tid; i < 2048; i += 256) lh[i] = 0u;
    __syncthreads();
    for (unsigned int i = tid; i < NS; i += 256) {
        unsigned int u = samp[i];
        if ((u >> 21) == B) atomicAdd(&lh[(u >> 10) & 2047u], 1u);
    }
    __syncthreads();
    part = 0u;
    for (int j = 0; j < 8; ++j) { unsigned int v = lh[2047 - (tid * 8 + j)]; loc[j] = v; part += v; }
    cum = block_exscan256(part, lds, tid);
    for (int j = 0; j < 8; ++j) {
        int bin = 2047 - (tid * 8 + j); unsigned int c = loc[j];
        if (cum < kr && cum + c >= kr) {
            unsigned int uhat = (B << 21) | ((unsigned int)bin << 10) | 512u;
            unsigned int half = WSIZE >> 1;
            unsigned int wlo = (uhat > half) ? (uhat - half) : 0u;
            unsigned int wlomax = 0u - WSIZE;
            if (wlo > wlomax) wlo = wlomax;
            sc[SC_WLO] = wlo;
        }
        cum += c;
    }
}

// ---- 3: the single full pass ----
__global__ void __launch_bounds__(256)
main_kernel(const float* __restrict__ x, float* __restrict__ out,
            int n4, long long N,
            unsigned int* __restrict__ fine, unsigned int* __restrict__ csum,
            unsigned int* __restrict__ gcoarse,
            unsigned int* __restrict__ segctr, uint2* __restrict__ list,
            unsigned int* __restrict__ sc)
{
    __shared__ unsigned int coarse[2048];
    __shared__ unsigned int bidx[2048];
    __shared__ unsigned int bval[2048];
    __shared__ unsigned int bcnt, bbase, bovf;
    __shared__ unsigned int wsum[4];
    int tid = threadIdx.x;
    for (int i = tid; i < 2048; i += 256) coarse[i] = 0u;
    if (tid == 0) { bcnt = 0u; bovf = 0u; }
    __syncthreads();
    unsigned int wlo = sc[SC_WLO], whi = wlo + WSIZE - 1u;
    const float4* x4 = (const float4*)x;
    float4* o4 = (float4*)out;
    int stride = gridDim.x * blockDim.x;
    unsigned int above = 0u;
    for (int i = blockIdx.x * blockDim.x + tid; i < n4; i += stride) {
        float4 v = x4[i]; float4 o; unsigned int b = (unsigned int)i * 4u;
        #define DO(comp, oc, lane) { unsigned int u = f2u(comp); \
            atomicAdd(&coarse[u >> 21], 1u); \
            if (u > whi) { oc = comp; ++above; } \
            else { oc = 0.0f; if (u >= wlo) { \
                unsigned int p = atomicAdd(&bcnt, 1u); \
                if (p < 2048u) { bidx[p] = b + lane; bval[p] = u; } else bovf = 1u; } } }
        DO(v.x, o.x, 0u) DO(v.y, o.y, 1u) DO(v.z, o.z, 2u) DO(v.w, o.w, 3u)
        #undef DO
        o4[i] = o;
    }
    long long t0 = (long long)n4 * 4;
    if (blockIdx.x == 0 && tid < (int)(N - t0)) {
        long long idx = t0 + tid; float v = x[idx]; unsigned int u = f2u(v);
        atomicAdd(&coarse[u >> 21], 1u);
        float o = 0.0f;
        if (u > whi) { o = v; ++above; }
        else if (u >= wlo) {
            unsigned int p = atomicAdd(&bcnt, 1u);
            if (p < 2048u) { bidx[p] = (unsigned int)idx; bval[p] = u; } else bovf = 1u;
        }
        out[idx] = o;
    }
    for (int o = 32; o; o >>= 1) above += __shfl_down(above, o, 64);
    if ((tid & 63) == 0) wsum[tid >> 6] = above;
    __syncthreads();
    if (tid == 0) {
        unsigned int s = wsum[0] + wsum[1] + wsum[2] + wsum[3];
        if (s) atomicAdd(&sc[SC_ABOVE], s);              // non-returning, 1/block
        unsigned int cnt = bcnt > 2048u ? 2048u : bcnt;
        unsigned int base = 0u;
        if (cnt) base = atomicAdd(&segctr[(blockIdx.x & 63u) * 16u], cnt); // 32 blocks/counter
        bbase = base;
        if (bovf || bcnt > 2048u || base + cnt > (unsigned int)SEGCAP)
            atomicAdd(&sc[SC_OVF], 1u);
    }
    __syncthreads();
    unsigned int cnt = bcnt > 2048u ? 2048u : bcnt;
    unsigned int base = bbase;
    uint2* mylist = list + (size_t)(blockIdx.x & 63u) * SEGCAP;
    for (unsigned int j = tid; j < cnt; j += 256u) {
        unsigned int pos = base + j;
        if (pos < (unsigned int)SEGCAP) mylist[pos] = make_uint2(bidx[j], bval[j]);
        unsigned int off = bval[j] - wlo;
        atomicAdd(&fine[off], 1u);
        atomicAdd(&csum[off >> 10], 1u);
    }
    for (int i = tid; i < 2048; i += 256) {
        unsigned int c = coarse[i];
        if (c) atomicAdd(&gcoarse[i], c);
    }
}

// ---- 4: threshold from csum+fine; always prep coarse-bin fallback ----
__global__ void __launch_bounds__(256)
final_kernel(const unsigned int* __restrict__ fine,
             const unsigned int* __restrict__ csum,
             const unsigned int* __restrict__ gcoarse,
             unsigned int* __restrict__ sc, unsigned int k)
{
    __shared__ unsigned int lds[256];
    __shared__ unsigned int sh2[2];
    __shared__ unsigned int s_total;
    int tid = threadIdx.x;
    unsigned int above = sc[SC_ABOVE];
    unsigned int ovf = sc[SC_OVF];
    unsigned int loc[4], part = 0u;
    for (int j = 0; j < 4; ++j) { unsigned int v = csum[1023 - (tid * 4 + j)]; loc[j] = v; part += v; }
    unsigned int ex = block_exscan256(part, lds, tid);
    if (tid == 255) s_total = ex + part;
    __syncthreads();
    unsigned int wtot = s_total;
    unsigned int valid = (!ovf) && (above < k) && ((k - above) <= wtot);
    if (tid == 0) sc[SC_OK] = valid;
    {   // exact coarse-bin fallback state (always)
        unsigned int l2[8], p2 = 0u;
        for (int j = 0; j < 8; ++j) { unsigned int v = gcoarse[2047 - (tid * 8 + j)]; l2[j] = v; p2 += v; }
        __syncthreads();
        unsigned int e2 = block_exscan256(p2, lds, tid);
        unsigned int cum = e2;
        for (int j = 0; j < 8; ++j) {
            int bin = 2047 - (tid * 8 + j); unsigned int c = l2[j];
            if (cum < k && cum + c >= k) { sc[SC_CB] = (unsigned int)bin; sc[SC_CBKR] = k - cum; }
            cum += c;
        }
    }
    if (!valid) return;
    unsigned int krem = k - above;
    __syncthreads();
    unsigned int cum = ex;
    for (int j = 0; j < 4; ++j) {
        int c = 1023 - (tid * 4 + j); unsigned int cc = loc[j];
        if (cum < krem && cum + cc >= krem) { sh2[0] = (unsigned int)c; sh2[1] = krem - cum; }
        cum += cc;
    }
    __syncthreads();
    unsigned int C = sh2[0], kr2 = sh2[1];
    unsigned int l3[4], p3 = 0u;
    for (int j = 0; j < 4; ++j) { unsigned int v = fine[C * 1024u + (1023u - (tid * 4 + j))]; l3[j] = v; p3 += v; }
    __syncthreads();
    unsigned int e3 = block_exscan256(p3, lds, tid);
    unsigned int cum3 = e3;
    for (int j = 0; j < 4; ++j) {
        unsigned int bin = 1023u - (tid * 4 + j); unsigned int cc = l3[j];
        if (cum3 < kr2 && cum3 + cc >= kr2) { sc[SC_TU] = sc[SC_WLO] + C * 1024u + bin; sc[SC_NEED] = kr2 - cum3; }
        cum3 += cc;
    }
}

// ---- 5: OK: patch winners from list; !OK: fallback fine-hist pass ----
__global__ void __launch_bounds__(256)
fix_kernel(const float* __restrict__ x, float* __restrict__ out,
           int n4, long long N,
           const unsigned int* __restrict__ segctr, const uint2* __restrict__ list,
           unsigned int* __restrict__ hist2, unsigned int* __restrict__ csum2,
           unsigned int* __restrict__ eq_list, unsigned int* __restrict__ sc)
{
    int tid = threadIdx.x;
    if (sc[SC_OK]) {
        unsigned int tu = sc[SC_TU];
        unsigned int seg = blockIdx.x & 63u, sub = blockIdx.x >> 6;
        unsigned int cnt = segctr[seg * 16u]; if (cnt > (unsigned int)SEGCAP) cnt = SEGCAP;
        const uint2* mylist = list + (size_t)seg * SEGCAP;
        for (unsigned int j = sub * 256u + tid; j < cnt; j += 32u * 256u) {
            uint2 e = mylist[j];
            if (e.y > tu) out[e.x] = u2f(e.y);
            else if (e.y == tu) {
                unsigned int p = atomicAdd(&sc[SC_EQN], 1u);
                if (p < (unsigned int)EQ_CAP) eq_list[p] = e.x;
            }
        }
    } else {
        unsigned int CB = sc[SC_CB];
        const float4* x4 = (const float4*)x;
        int stride = gridDim.x * blockDim.x;
        for (int i = blockIdx.x * blockDim.x + tid; i < n4; i += stride) {
            float4 v = x4[i];
            #define FB(c) { unsigned int u = f2u(c); if ((u >> 21) == CB) { \
                unsigned int off = u & 0x1FFFFFu; atomicAdd(&hist2[off], 1u); atomicAdd(&csum2[off >> 10], 1u); } }
            FB(v.x) FB(v.y) FB(v.z) FB(v.w)
            #undef FB
        }
        long long t0 = (long long)n4 * 4;
        if (blockIdx.x == 0 && tid < (int)(N - t0)) {
            unsigned int u = f2u(x[t0 + tid]);
            if ((u >> 21) == CB) {
                unsigned int off = u & 0x1FFFFFu;
                atomicAdd(&hist2[off], 1u); atomicAdd(&csum2[off >> 10], 1u);
            }
        }
    }
}

// ---- 6: OK: stable tie-fix; !OK: fallback scan -> t_u ----
__global__ void __launch_bounds__(256)
post_kernel(const unsigned int* __restrict__ hist2,
            const unsigned int* __restrict__ csum2,
            float* __restrict__ out, const unsigned int* __restrict__ eq_list,
            unsigned int* __restrict__ sc)
{
    __shared__ unsigned int lds[256];
    __shared__ unsigned int sh2[2];
    int tid = threadIdx.x;
    if (sc[SC_OK]) {
        unsigned int m = sc[SC_EQN]; if (m > (unsigned int)EQ_CAP) m = EQ_CAP;
        unsigned int need = sc[SC_NEED];
        float f = u2f(sc[SC_TU]);
        for (unsigned int j = tid; j < m; j += 256u) {
            unsigned int idx = eq_list[j]; unsigned int c = 0u;
            for (unsigned int l = 0; l < m; ++l) c += (eq_list[l] < idx) ? 1u : 0u;
            if (c < need) out[idx] = f;
        }
    } else {
        unsigned int CB = sc[SC_CB], kr = sc[SC_CBKR];
        unsigned int loc[8], part = 0u;
        for (int j = 0; j < 8; ++j) { unsigned int v = csum2[2047 - (tid * 8 + j)]; loc[j] = v; part += v; }
        unsigned int ex = block_exscan256(part, lds, tid);
        unsigned int cum = ex;
        for (int j = 0; j < 8; ++j) {
            int c = 2047 - (tid * 8 + j); unsigned int cc = loc[j];
            if (cum < kr && cum + cc >= kr) { sh2[0] = (unsigned int)c; sh2[1] = kr - cum; }
            cum += cc;
        }
        __syncthreads();
        unsigned int C2 = sh2[0], kr2 = sh2[1];
        unsigned int l3[4], p3 = 0u;
        for (int j = 0; j < 4; ++j) { unsigned int v = hist2[C2 * 1024u + (1023u - (tid * 4 + j))]; l3[j] = v; p3 += v; }
        __syncthreads();
        unsigned int e3 = block_exscan256(p3, lds, tid);
        unsigned int cum3 = e3;
        for (int j = 0; j < 4; ++j) {
            unsigned int bin = 1023u - (tid * 4 + j); unsigned int cc = l3[j];
            if (cum3 < kr2 && cum3 + cc >= kr2) { sc[SC_TU] = (CB << 21) | (C2 * 1024u + bin); sc[SC_NEED] = kr2 - cum3; }
            cum3 += cc;
        }
    }
}

// ---- 7: full exact re-scatter (no-op when OK) ----
__global__ void __launch_bounds__(256)
fb_scatter_kernel(const float* __restrict__ x, int n4, long long N,
                  float* __restrict__ out, unsigned int* __restrict__ sc,
                  unsigned int* __restrict__ eq_list)
{
    if (sc[SC_OK]) return;
    int tid = threadIdx.x;
    unsigned int tu = sc[SC_TU];
    const float4* x4 = (const float4*)x;
    float4* o4 = (float4*)out;
    int stride = gridDim.x * blockDim.x;
    for (int i = blockIdx.x * blockDim.x + tid; i < n4; i += stride) {
        float4 v = x4[i];
        unsigned int u0 = f2u(v.x), u1 = f2u(v.y), u2 = f2u(v.z), u3 = f2u(v.w);
        float4 o;
        o.x = (u0 > tu) ? v.x : 0.0f;
        o.y = (u1 > tu) ? v.y : 0.0f;
        o.z = (u2 > tu) ? v.z : 0.0f;
        o.w = (u3 > tu) ? v.w : 0.0f;
        if (u0 == tu || u1 == tu || u2 == tu || u3 == tu) {
            unsigned int b = (unsigned int)i * 4u;
            if (u0 == tu) { unsigned int p = atomicAdd(&sc[SC_EQN], 1u); if (p < (unsigned int)EQ_CAP) eq_list[p] = b + 0u; }
            if (u1 == tu) { unsigned int p = atomicAdd(&sc[SC_EQN], 1u); if (p < (unsigned int)EQ_CAP) eq_list[p] = b + 1u; }
            if (u2 == tu) { unsigned int p = atomicAdd(&sc[SC_EQN], 1u); if (p < (unsigned int)EQ_CAP) eq_list[p] = b + 2u; }
            if (u3 == tu) { unsigned int p = atomicAdd(&sc[SC_EQN], 1u); if (p < (unsigned int)EQ_CAP) eq_list[p] = b + 3u; }
        }
        o4[i] = o;
    }
    long long t0 = (long long)n4 * 4;
    if (blockIdx.x == 0 && tid < (int)(N - t0)) {
        long long idx = t0 + tid;
        float v = x[idx]; unsigned int u = f2u(v);
        out[idx] = (u > tu) ? v : 0.0f;
        if (u == tu) { unsigned int p = atomicAdd(&sc[SC_EQN], 1u); if (p < (unsigned int)EQ_CAP) eq_list[p] = (unsigned int)idx; }
    }
}

// ---- 8: tie-fix for fallback path (no-op when OK) ----
__global__ void __launch_bounds__(256)
fb_post_kernel(float* __restrict__ out, const unsigned int* __restrict__ sc,
               const unsigned int* __restrict__ eq_list)
{
    if (sc[SC_OK]) return;
    unsigned int m = sc[SC_EQN]; if (m > (unsigned int)EQ_CAP) m = EQ_CAP;
    unsigned int need = sc[SC_NEED];
    float f = u2f(sc[SC_TU]);
    for (unsigned int j = threadIdx.x; j < m; j += blockDim.x) {
        unsigned int idx = eq_list[j]; unsigned int c = 0u;
        for (unsigned int l = 0; l < m; ++l) c += (eq_list[l] < idx) ? 1u : 0u;
        if (c < need) out[idx] = f;
    }
}

extern "C" void kernel_launch(void* const* d_in, const int* in_sizes, int n_in,
                              void* d_out, int out_size, void* d_ws, size_t ws_size,
                              hipStream_t stream) {
    const float* x = (const float*)d_in[0];
    float* out = (float*)d_out;
    long long N = (long long)in_sizes[0];
    int n4 = (int)(N >> 2);
    unsigned int k = (unsigned int)((double)N * 0.1);
    if (k == 0u) k = 1u;

    unsigned int NS = 65536u;
    unsigned int ks = (unsigned int)((double)NS * (double)k / (double)N);
    if (ks < 1u) ks = 1u; if (ks > NS) ks = NS;

    // ws layout (32 MB used):
    // 0       sc (1 KB) | 1K segctr (4 KB) | 8K csum (4 KB) | 16K csum2 (8 KB)
    // 24K     gcoarse (8 KB) | 32K eq_list (256 KB) | 288K samp (256 KB)
    // 1M      fine (4 MB) | 8M hist2 (8 MB) | 16M list (16 MB)
    uint8_t* w = (uint8_t*)d_ws;
    unsigned int* sc      = (unsigned int*)w;
    unsigned int* segctr  = (unsigned int*)(w + 1024);
    unsigned int* csum    = (unsigned int*)(w + 8192);
    unsigned int* csum2   = (unsigned int*)(w + 16384);
    unsigned int* gcoarse = (unsigned int*)(w + 24576);
    unsigned int* eq_list = (unsigned int*)(w + 32768);
    unsigned int* samp    = (unsigned int*)(w + 294912);
    unsigned int* fine    = (unsigned int*)(w + ((size_t)1 << 20));
    unsigned int* hist2   = (unsigned int*)(w + ((size_t)8 << 20));
    uint2*        list    = (uint2*)       (w + ((size_t)16 << 20));

    prep_kernel<<<256, BLK, 0, stream>>>(x, N, samp, fine, hist2, sc);
    refine_kernel<<<1, BLK, 0, stream>>>(samp, sc, ks, NS);
    main_kernel<<<MAIN_GRID, BLK, 0, stream>>>(x, out, n4, N, fine, csum,
                                               gcoarse, segctr, list, sc);
    final_kernel<<<1, BLK, 0, stream>>>(fine, csum, gcoarse, sc, k);
    fix_kernel<<<MAIN_GRID, BLK, 0, stream>>>(x, out, n4, N, segctr, list,
                                              hist2, csum2, eq_list, sc);
    post_kernel<<<1, BLK, 0, stream>>>(hist2, csum2, out, eq_list, sc);
    fb_scatter_kernel<<<MAIN_GRID, BLK, 0, stream>>>(x, n4, N, out, sc, eq_list);
    fb_post_kernel<<<1, BLK, 0, stream>>>(out, sc, eq_list);
}